// Round 1
// 425.722 us; speedup vs baseline: 1.1306x; 1.1306x over previous
//
#include <hip/hip_runtime.h>
#include <hip/hip_bf16.h>

// VQ-MoE R7: vq_mfma rework —
//  (1) v_cvt_pk_bf16_f32 split conversion (~2.3x less staging VALU),
//  (2) linear swizzled LDS (chunk ^= (row>>1)&3, 16B units): no padding,
//      conflict-free b128 fragment reads, 41.5->33 KB => 4 blocks/CU,
//  (3) global_load_lds(16B) for the B (codebook) tile with pre-swizzled
//      global source (rule: linear dest + inverse-swz source + swz read),
//  (4) launch_bounds(512,8).
// Also: compact fused into combine (one fewer launch), zsq widened to 1024 blocks.

#define EPS_GAP 2e-3f
#define NTOK 65536

typedef __attribute__((ext_vector_type(8))) short bf16x8;
typedef __attribute__((ext_vector_type(4))) float f32x4;

__device__ inline unsigned short f2bf(float f) {
  __hip_bfloat16 h = __float2bfloat16(f);
  unsigned short u;
  __builtin_memcpy(&u, &h, 2);
  return u;
}
__device__ inline float bf2f(unsigned short u) {
  return __uint_as_float(((unsigned)u) << 16);
}

__device__ inline void gll16(const unsigned short* g, unsigned short* l) {
  __builtin_amdgcn_global_load_lds(
      (const __attribute__((address_space(1))) unsigned int*)g,
      (__attribute__((address_space(3))) unsigned int*)l, 16, 0, 0);
}

// ---------------- csum + codebook split (+ zero worklist counter) ----------------
__global__ __launch_bounds__(256) void csum_split_kernel(
    const float* __restrict__ cb0, const float* __restrict__ cb1,
    const float* __restrict__ cb2, const float* __restrict__ cb3,
    float* __restrict__ csums, double* __restrict__ csums64,
    unsigned short* __restrict__ cb_hi, unsigned short* __restrict__ cb_lo,
    int* __restrict__ wl_cnt) {
  if (blockIdx.x == 0 && threadIdx.x == 0) wl_cnt[0] = 0;  // stream-ordered init
  int row = blockIdx.x * 4 + (threadIdx.x >> 6);
  int lane = threadIdx.x & 63;
  const float* src; int r;
  if (row < 256)       { src = cb0; r = row; }
  else if (row < 768)  { src = cb1; r = row - 256; }
  else if (row < 1792) { src = cb2; r = row - 768; }
  else                 { src = cb3; r = row - 1792; }
  float4 v = ((const float4*)(src + r * 256))[lane];
  unsigned short h0 = f2bf(v.x), h1 = f2bf(v.y), h2 = f2bf(v.z), h3 = f2bf(v.w);
  unsigned short l0 = f2bf(v.x - bf2f(h0)), l1 = f2bf(v.y - bf2f(h1));
  unsigned short l2 = f2bf(v.z - bf2f(h2)), l3 = f2bf(v.w - bf2f(h3));
  *(ushort4*)(cb_hi + (size_t)row * 256 + lane * 4) = make_ushort4(h0, h1, h2, h3);
  *(ushort4*)(cb_lo + (size_t)row * 256 + lane * 4) = make_ushort4(l0, l1, l2, l3);
  double s = (double)v.x*v.x + (double)v.y*v.y + (double)v.z*v.z + (double)v.w*v.w;
  #pragma unroll
  for (int off = 32; off >= 1; off >>= 1) s += __shfl_down(s, off, 64);
  if (lane == 0) { csums[row] = (float)s; csums64[row] = s; }
}

// ---------------- zsq: sum of all z^2 (fp64 partials) ----------------
__global__ __launch_bounds__(256) void zsq_kernel(const float* __restrict__ z,
                                                  double* __restrict__ parts) {
  const float4* p = (const float4*)z;
  const int n4 = 4194304;
  double s = 0.0;
  for (int i = blockIdx.x * 256 + threadIdx.x; i < n4; i += 256 * 1024) {
    float4 v = p[i];
    s += (double)v.x*(double)v.x + (double)v.y*(double)v.y
       + (double)v.z*(double)v.z + (double)v.w*(double)v.w;
  }
  #pragma unroll
  for (int off = 32; off >= 1; off >>= 1) s += __shfl_down(s, off, 64);
  __shared__ double sh[4];
  if ((threadIdx.x & 63) == 0) sh[threadIdx.x >> 6] = s;
  __syncthreads();
  if (threadIdx.x == 0) parts[blockIdx.x] = sh[0] + sh[1] + sh[2] + sh[3];
}

// ---------------- main: MFMA distances + argmin(+2nd) partials ----------------
// LDS layout: linear [128 rows][32 ushorts] per array; 16B-chunk swizzle
// c' = c ^ ((row>>1)&3). Verified conflict-free for b128 fragment reads.
__global__ __launch_bounds__(512, 8) void vq_mfma(
    const float* __restrict__ z_e, const int* __restrict__ expert_idx,
    const unsigned short* __restrict__ cb_hi, const unsigned short* __restrict__ cb_lo,
    const float* __restrict__ csums,
    float* __restrict__ D1, int* __restrict__ K1, float* __restrict__ D2) {
  const int b  = blockIdx.y;
  const int e  = expert_idx[b];
  const int hc = blockIdx.z;
  if (hc >= (2 << e)) return;               // inert (uniform exit)
  const int cs_off = (e == 0) ? 0 : (e == 1) ? 256 : (e == 2) ? 768 : 1792;
  const int krow0  = cs_off + hc * 128;
  const int t0     = b * 1024 + blockIdx.x * 128;

  __shared__ unsigned short smem[4 * 128 * 32];   // Ah, Al, Bh, Bl  (32 KB)
  __shared__ float  sh_cs[128];
  unsigned short* Ah = smem;
  unsigned short* Al = smem + 128 * 32;
  unsigned short* Bh = smem + 2 * 128 * 32;
  unsigned short* Bl = smem + 3 * 128 * 32;

  const int tid = threadIdx.x;
  if (tid < 128) sh_cs[tid] = csums[krow0 + tid];

  const int w = tid >> 6, l = tid & 63;
  const int h = w >> 2, q = w & 3;
  const int m16 = l & 15, g = l >> 4;

  // B staging via global_load_lds: wave w fills rows w*16..w*16+15 linearly.
  // lane l -> LDS (row = w*16 + (l>>2), chunk = l&3); source chunk pre-swizzled.
  const int brow   = w * 16 + (l >> 2);
  const int bchunk = (l & 3) ^ ((brow >> 1) & 3);
  const size_t bsrc0 = (size_t)(krow0 + brow) * 256 + (size_t)bchunk * 8;
  unsigned short* bh_dst = Bh + w * 512;    // wave-uniform LDS base
  unsigned short* bl_dst = Bl + w * 512;

  f32x4 acc[4][2];
  #pragma unroll
  for (int i = 0; i < 4; ++i)
    #pragma unroll
    for (int j = 0; j < 2; ++j) acc[i][j] = (f32x4){0.f, 0.f, 0.f, 0.f};

  for (int kp = 0; kp < 8; ++kp) {
    const int kc = kp * 32;
    __syncthreads();
    // B tile: issue async loads first (latency hides under A conversion)
    gll16(cb_hi + bsrc0 + kc, bh_dst);
    gll16(cb_lo + bsrc0 + kc, bl_dst);
    // A tile: f32 -> split bf16 via v_cvt_pk, swizzled ds_write
    #pragma unroll
    for (int it = 0; it < 2; ++it) {
      int idx = tid + it * 512;
      int row = idx >> 3, seg = idx & 7;
      float4 v = *(const float4*)(z_e + (size_t)(t0 + row) * 256 + kc + seg * 4);
      unsigned hxy, hzw, lxy, lzw;
      asm("v_cvt_pk_bf16_f32 %0, %1, %2" : "=v"(hxy) : "v"(v.x), "v"(v.y));
      asm("v_cvt_pk_bf16_f32 %0, %1, %2" : "=v"(hzw) : "v"(v.z), "v"(v.w));
      float lx = v.x - __uint_as_float(hxy << 16);
      float ly = v.y - __uint_as_float(hxy & 0xffff0000u);
      float lz = v.z - __uint_as_float(hzw << 16);
      float lw = v.w - __uint_as_float(hzw & 0xffff0000u);
      asm("v_cvt_pk_bf16_f32 %0, %1, %2" : "=v"(lxy) : "v"(lx), "v"(ly));
      asm("v_cvt_pk_bf16_f32 %0, %1, %2" : "=v"(lzw) : "v"(lz), "v"(lw));
      int off = row * 32 + ((((seg >> 1) ^ ((row >> 1) & 3)) << 3) | ((seg & 1) << 2));
      *(uint2*)(Ah + off) = make_uint2(hxy, hzw);
      *(uint2*)(Al + off) = make_uint2(lxy, lzw);
    }
    __syncthreads();
    bf16x8 bh[2], bl[2];
    #pragma unroll
    for (int j = 0; j < 2; ++j) {
      int r = q * 32 + j * 16 + m16;
      int n = r * 32 + ((g ^ ((r >> 1) & 3)) << 3);
      bh[j] = *(bf16x8*)(Bh + n);
      bl[j] = *(bf16x8*)(Bl + n);
    }
    #pragma unroll
    for (int i = 0; i < 4; ++i) {
      int r = h * 64 + i * 16 + m16;
      int a = r * 32 + ((g ^ ((r >> 1) & 3)) << 3);
      bf16x8 ah = *(bf16x8*)(Ah + a);
      bf16x8 al = *(bf16x8*)(Al + a);
      #pragma unroll
      for (int j = 0; j < 2; ++j) {
        acc[i][j] = __builtin_amdgcn_mfma_f32_16x16x32_bf16(ah, bh[j], acc[i][j], 0, 0, 0);
        acc[i][j] = __builtin_amdgcn_mfma_f32_16x16x32_bf16(al, bh[j], acc[i][j], 0, 0, 0);
        acc[i][j] = __builtin_amdgcn_mfma_f32_16x16x32_bf16(ah, bl[j], acc[i][j], 0, 0, 0);
      }
    }
  }

  __syncthreads();
  float* mD = (float*)smem;
  int*   mK = (int*)(smem + 1024);
  float* mS = (float*)(smem + 2048);

  #pragma unroll
  for (int i = 0; i < 4; ++i) {
    #pragma unroll
    for (int r = 0; r < 4; ++r) {
      int k0 = q * 32 + m16;
      float d0 = sh_cs[k0]      - 2.0f * acc[i][0][r];
      float d1 = sh_cs[k0 + 16] - 2.0f * acc[i][1][r];
      float bv, sv; int bk;
      if (d0 <= d1) { bv = d0; bk = k0; sv = d1; }
      else          { bv = d1; bk = k0 + 16; sv = d0; }
      #pragma unroll
      for (int off = 8; off >= 1; off >>= 1) {
        float ov = __shfl_xor(bv, off);
        int   ok = __shfl_xor(bk, off);
        float os = __shfl_xor(sv, off);
        float nb; int nk;
        if (ov < bv || (ov == bv && ok < bk)) { nb = ov; nk = ok; }
        else                                  { nb = bv; nk = bk; }
        sv = fminf(fmaxf(bv, ov), fminf(sv, os));
        bv = nb; bk = nk;
      }
      if (m16 == 0) {
        int tloc = h * 64 + i * 16 + g * 4 + r;
        mD[tloc * 4 + q] = bv;
        mK[tloc * 4 + q] = bk;
        mS[tloc * 4 + q] = sv;
      }
    }
  }
  __syncthreads();
  if (tid < 128) {
    float B = 3.4e38f, S = 3.4e38f; int Kb = 0;
    #pragma unroll
    for (int c = 0; c < 4; ++c) {
      float d1v = mD[tid * 4 + c];
      int   k1v = mK[tid * 4 + c];
      float d2v = mS[tid * 4 + c];
      S = fminf(fmaxf(B, d1v), fminf(S, d2v));
      if (d1v < B) { B = d1v; Kb = k1v; }
    }
    int tg = t0 + tid;
    D1[hc * NTOK + tg] = B;
    K1[hc * NTOK + tg] = hc * 128 + Kb;
    D2[hc * NTOK + tg] = S;
  }
}

// ---------------- combine: merge half-chunks -> idx, worklist, loss partials ----------------
__global__ __launch_bounds__(256) void combine_kernel(
    const int* __restrict__ expert_idx,
    const float* __restrict__ D1, const int* __restrict__ K1,
    const float* __restrict__ D2,
    float* __restrict__ idx_out,
    int* __restrict__ wl, int* __restrict__ wl_cnt,
    double* __restrict__ parts) {
  const int t = blockIdx.x * 256 + threadIdx.x;
  const int e = expert_idx[t >> 10];
  const int nch = 2 << e;
  float B = 3.4e38f, S = 3.4e38f; int Kb = 0;
  for (int c = 0; c < nch; ++c) {
    float d1 = D1[c * NTOK + t];
    int   k1 = K1[c * NTOK + t];
    float d2 = D2[c * NTOK + t];
    S = fminf(fmaxf(B, d1), fminf(S, d2));
    if (d1 < B) { B = d1; Kb = k1; }
  }
  idx_out[t] = (float)Kb;
  if (S - B < EPS_GAP) {                     // fused compact
    int p = atomicAdd(wl_cnt, 1);
    wl[p] = t;
  }
  double s = (double)B;
  #pragma unroll
  for (int off = 32; off >= 1; off >>= 1) s += __shfl_down(s, off, 64);
  __shared__ double sh[4];
  if ((threadIdx.x & 63) == 0) sh[threadIdx.x >> 6] = s;
  __syncthreads();
  if (threadIdx.x == 0) parts[blockIdx.x] = sh[0] + sh[1] + sh[2] + sh[3];
}

// ---------------- zq gather: one wave per token ----------------
__global__ __launch_bounds__(256) void zq_gather_kernel(
    const int* __restrict__ expert_idx,
    const float* __restrict__ cb0, const float* __restrict__ cb1,
    const float* __restrict__ cb2, const float* __restrict__ cb3,
    const float* __restrict__ idx_out, float* __restrict__ zq_out) {
  const int tok  = blockIdx.x * 4 + (threadIdx.x >> 6);
  const int lane = threadIdx.x & 63;
  const int e = expert_idx[tok >> 10];
  const float* cb = (e == 0) ? cb0 : (e == 1) ? cb1 : (e == 2) ? cb2 : cb3;
  const int row = (int)idx_out[tok];
  ((float4*)(zq_out + (size_t)tok * 256))[lane] =
      ((const float4*)(cb + (size_t)row * 256))[lane];
}

// ---------------- rescue: numpy-fp32-EMULATED re-rank, one block per flagged token ----------------
__global__ __launch_bounds__(256) void rescue_kernel(
    const float* __restrict__ z_e, const int* __restrict__ expert_idx,
    const float* __restrict__ cb0, const float* __restrict__ cb1,
    const float* __restrict__ cb2, const float* __restrict__ cb3,
    const double* __restrict__ csums64,
    const int* __restrict__ wl, const int* __restrict__ wl_cnt,
    float* __restrict__ zq_out, float* __restrict__ idx_out) {
  __shared__ float  szrow[256];
  __shared__ double szs[4];
  __shared__ float  sdv[3][256];
  __shared__ int    skv[3][256];
  __shared__ int    s_kc;
  const int tid = threadIdx.x;
  const int wid = tid >> 6, lane = tid & 63;
  const int n = wl_cnt[0];
  for (int it = blockIdx.x; it < n; it += gridDim.x) {
    const int t = wl[it];
    const int b = t >> 10;
    const int e = expert_idx[b];
    const int K = 256 << e;
    const float* cb = (e == 0) ? cb0 : (e == 1) ? cb1 : (e == 2) ? cb2 : cb3;
    const int off = (e == 0) ? 0 : (e == 1) ? 256 : (e == 2) ? 768 : 1792;
    const double* cs64 = csums64 + off;

    __syncthreads();                       // protect shared reuse across iterations
    float zv = z_e[(size_t)t * 256 + tid];
    szrow[tid] = zv;
    double zsq = (double)zv * (double)zv;
    #pragma unroll
    for (int o = 32; o >= 1; o >>= 1) zsq += __shfl_down(zsq, o, 64);
    if (lane == 0) szs[wid] = zsq;
    __syncthreads();
    const float zs_mid = (float)(szs[0] + szs[1] + szs[2] + szs[3]);
    const unsigned zu = __float_as_uint(zs_mid);
    float zs[3] = {__uint_as_float(zu - 1), zs_mid, __uint_as_float(zu + 1)};

    float bd[3] = {3.4e38f, 3.4e38f, 3.4e38f};
    int   bk[3] = {1 << 30, 1 << 30, 1 << 30};
    const float4* z4 = (const float4*)szrow;
    for (int k = tid; k < K; k += 256) {
      const float4* c4 = (const float4*)(cb + (size_t)k * 256);
      double d0 = 0.0, d1v = 0.0, d2v = 0.0, d3 = 0.0;   // 4 indep chains
      for (int qq = 0; qq < 64; qq += 4) {
        float4 a0 = z4[qq],     c0 = c4[qq];
        float4 a1 = z4[qq + 1], c1 = c4[qq + 1];
        float4 a2 = z4[qq + 2], c2 = c4[qq + 2];
        float4 a3 = z4[qq + 3], c3 = c4[qq + 3];
        d0 += (double)a0.x*c0.x + (double)a0.y*c0.y + (double)a0.z*c0.z + (double)a0.w*c0.w;
        d1v+= (double)a1.x*c1.x + (double)a1.y*c1.y + (double)a1.z*c1.z + (double)a1.w*c1.w;
        d2v+= (double)a2.x*c2.x + (double)a2.y*c2.y + (double)a2.z*c2.z + (double)a2.w*c2.w;
        d3 += (double)a3.x*c3.x + (double)a3.y*c3.y + (double)a3.z*c3.z + (double)a3.w*c3.w;
      }
      double dot = (d0 + d1v) + (d2v + d3);
      const float c32 = (float)cs64[k];
      const float m2d = (float)(2.0 * dot);
      #pragma unroll
      for (int v = 0; v < 3; ++v) {
        float T1  = zs[v] + c32;           // numpy order: (zsum+csum) - 2dot
        float d32 = T1 - m2d;
        if (d32 < bd[v]) { bd[v] = d32; bk[v] = k; }
      }
    }
    #pragma unroll
    for (int v = 0; v < 3; ++v) { sdv[v][tid] = bd[v]; skv[v][tid] = bk[v]; }
    __syncthreads();
    for (int s = 128; s >= 1; s >>= 1) {
      if (tid < s) {
        #pragma unroll
        for (int v = 0; v < 3; ++v) {
          float od = sdv[v][tid + s]; int ok = skv[v][tid + s];
          if (od < sdv[v][tid] || (od == sdv[v][tid] && ok < skv[v][tid])) {
            sdv[v][tid] = od; skv[v][tid] = ok;
          }
        }
      }
      __syncthreads();
    }
    if (tid == 0) {
      int k0 = skv[0][0], k1 = skv[1][0], k2 = skv[2][0];
      int kc = (k0 == k2) ? k0 : k1;       // majority vote over zsum ulp variants
      s_kc = kc;
      idx_out[t] = (float)kc;
    }
    __syncthreads();
    const int kc = s_kc;
    if (tid < 64)
      ((float4*)(zq_out + (size_t)t * 256))[tid] =
          ((const float4*)(cb + (size_t)kc * 256))[tid];
  }
}

// ---------------- finalize: loss = 1.25*(S_comb + S_zsq)/2^32 ----------------
__global__ __launch_bounds__(256) void finalize_kernel(
    const double* __restrict__ parts_comb, const double* __restrict__ parts_zsq,
    float* __restrict__ loss_out) {
  const int tid = threadIdx.x;
  double s = parts_comb[tid] + parts_zsq[tid] + parts_zsq[tid + 256]
           + parts_zsq[tid + 512] + parts_zsq[tid + 768];
  #pragma unroll
  for (int off = 32; off >= 1; off >>= 1) s += __shfl_down(s, off, 64);
  __shared__ double sh[4];
  if ((tid & 63) == 0) sh[tid >> 6] = s;
  __syncthreads();
  if (tid == 0)
    loss_out[0] = (float)((sh[0] + sh[1] + sh[2] + sh[3]) * (1.25 / 4294967296.0));
}

extern "C" void kernel_launch(void* const* d_in, const int* in_sizes, int n_in,
                              void* d_out, int out_size, void* d_ws, size_t ws_size,
                              hipStream_t stream) {
  const float* z_e  = (const float*)d_in[0];
  const int*   eidx = (const int*)d_in[1];
  const float* cb0  = (const float*)d_in[2];
  const float* cb1  = (const float*)d_in[3];
  const float* cb2  = (const float*)d_in[4];
  const float* cb3  = (const float*)d_in[5];

  float* zq    = (float*)d_out;                       // 64*1024*256
  float* idxf  = (float*)d_out + 16777216;            // 64*1024 as floats
  float* lossf = (float*)d_out + 16777216 + 65536;    // 1

  char* wsp = (char*)d_ws;
  double*         parts_comb = (double*)wsp;           wsp += 256 * 8;
  double*         parts_zsq  = (double*)wsp;           wsp += 1024 * 8;
  double*         csums64    = (double*)wsp;           wsp += 3840 * 8;
  float*          csums      = (float*)wsp;            wsp += 3840 * 4;
  int*            wl_cnt     = (int*)wsp;              wsp += 16;
  int*            wl         = (int*)wsp;              wsp += NTOK * 4;
  unsigned short* cb_hi      = (unsigned short*)wsp;   wsp += 3840 * 256 * 2;
  unsigned short* cb_lo      = (unsigned short*)wsp;   wsp += 3840 * 256 * 2;
  float*          D1         = (float*)wsp;            wsp += 16 * NTOK * 4;
  int*            K1         = (int*)wsp;              wsp += 16 * NTOK * 4;
  float*          D2         = (float*)wsp;            wsp += 16 * NTOK * 4;

  csum_split_kernel<<<960, 256, 0, stream>>>(cb0, cb1, cb2, cb3,
                                             csums, csums64, cb_hi, cb_lo, wl_cnt);
  zsq_kernel<<<1024, 256, 0, stream>>>(z_e, parts_zsq);
  dim3 grid(8, 64, 16);
  vq_mfma<<<grid, 512, 0, stream>>>(z_e, eidx, cb_hi, cb_lo, csums, D1, K1, D2);
  combine_kernel<<<256, 256, 0, stream>>>(eidx, D1, K1, D2, idxf, wl, wl_cnt, parts_comb);
  zq_gather_kernel<<<16384, 256, 0, stream>>>(eidx, cb0, cb1, cb2, cb3, idxf, zq);
  rescue_kernel<<<2048, 256, 0, stream>>>(z_e, eidx, cb0, cb1, cb2, cb3,
                                          csums64, wl, wl_cnt, zq, idxf);
  finalize_kernel<<<1, 256, 0, stream>>>(parts_comb, parts_zsq, lossf);
}

// Round 2
// 396.552 us; speedup vs baseline: 1.2138x; 1.0736x over previous
//
#include <hip/hip_runtime.h>
#include <hip/hip_bf16.h>

// VQ-MoE R8: pipelined vq_mfma.
//  - launch_bounds(512,4): 128-reg budget, kills R7's scratch spills
//    (R7 (512,8) => 64-reg cap => ~205 MB spill WRITE traffic, flat perf).
//  - 2-phase software pipeline (T3/T4-minimal): A tile prefetched to regs
//    one kp ahead; B tile global_load_lds into DOUBLE buffer one kp ahead;
//    raw s_barrier + counted "s_waitcnt vmcnt(4)" so prefetch loads stay in
//    flight across barriers (never a full vmcnt(0) drain in steady state).
//  - LDS: Ah,Al single + Bh,Bl double = 48 KB, conflict-free 16B-chunk
//    XOR swizzle (c ^= (row>>1)&3) as in R7 (verified, conflicts == 0).

#define EPS_GAP 2e-3f
#define NTOK 65536

typedef __attribute__((ext_vector_type(8))) short bf16x8;
typedef __attribute__((ext_vector_type(4))) float f32x4;

__device__ inline unsigned short f2bf(float f) {
  __hip_bfloat16 h = __float2bfloat16(f);
  unsigned short u;
  __builtin_memcpy(&u, &h, 2);
  return u;
}
__device__ inline float bf2f(unsigned short u) {
  return __uint_as_float(((unsigned)u) << 16);
}

__device__ inline void gll16(const unsigned short* g, unsigned short* l) {
  __builtin_amdgcn_global_load_lds(
      (const __attribute__((address_space(1))) unsigned int*)g,
      (__attribute__((address_space(3))) unsigned int*)l, 16, 0, 0);
}

// ---------------- csum + codebook split (+ zero worklist counter) ----------------
__global__ __launch_bounds__(256) void csum_split_kernel(
    const float* __restrict__ cb0, const float* __restrict__ cb1,
    const float* __restrict__ cb2, const float* __restrict__ cb3,
    float* __restrict__ csums, double* __restrict__ csums64,
    unsigned short* __restrict__ cb_hi, unsigned short* __restrict__ cb_lo,
    int* __restrict__ wl_cnt) {
  if (blockIdx.x == 0 && threadIdx.x == 0) wl_cnt[0] = 0;  // stream-ordered init
  int row = blockIdx.x * 4 + (threadIdx.x >> 6);
  int lane = threadIdx.x & 63;
  const float* src; int r;
  if (row < 256)       { src = cb0; r = row; }
  else if (row < 768)  { src = cb1; r = row - 256; }
  else if (row < 1792) { src = cb2; r = row - 768; }
  else                 { src = cb3; r = row - 1792; }
  float4 v = ((const float4*)(src + r * 256))[lane];
  unsigned short h0 = f2bf(v.x), h1 = f2bf(v.y), h2 = f2bf(v.z), h3 = f2bf(v.w);
  unsigned short l0 = f2bf(v.x - bf2f(h0)), l1 = f2bf(v.y - bf2f(h1));
  unsigned short l2 = f2bf(v.z - bf2f(h2)), l3 = f2bf(v.w - bf2f(h3));
  *(ushort4*)(cb_hi + (size_t)row * 256 + lane * 4) = make_ushort4(h0, h1, h2, h3);
  *(ushort4*)(cb_lo + (size_t)row * 256 + lane * 4) = make_ushort4(l0, l1, l2, l3);
  double s = (double)v.x*v.x + (double)v.y*v.y + (double)v.z*v.z + (double)v.w*v.w;
  #pragma unroll
  for (int off = 32; off >= 1; off >>= 1) s += __shfl_down(s, off, 64);
  if (lane == 0) { csums[row] = (float)s; csums64[row] = s; }
}

// ---------------- zsq: sum of all z^2 (fp64 partials) ----------------
__global__ __launch_bounds__(256) void zsq_kernel(const float* __restrict__ z,
                                                  double* __restrict__ parts) {
  const float4* p = (const float4*)z;
  const int n4 = 4194304;
  double s = 0.0;
  for (int i = blockIdx.x * 256 + threadIdx.x; i < n4; i += 256 * 1024) {
    float4 v = p[i];
    s += (double)v.x*(double)v.x + (double)v.y*(double)v.y
       + (double)v.z*(double)v.z + (double)v.w*(double)v.w;
  }
  #pragma unroll
  for (int off = 32; off >= 1; off >>= 1) s += __shfl_down(s, off, 64);
  __shared__ double sh[4];
  if ((threadIdx.x & 63) == 0) sh[threadIdx.x >> 6] = s;
  __syncthreads();
  if (threadIdx.x == 0) parts[blockIdx.x] = sh[0] + sh[1] + sh[2] + sh[3];
}

// ---------------- main: MFMA distances + argmin(+2nd) partials ----------------
__global__ __launch_bounds__(512, 4) void vq_mfma(
    const float* __restrict__ z_e, const int* __restrict__ expert_idx,
    const unsigned short* __restrict__ cb_hi, const unsigned short* __restrict__ cb_lo,
    const float* __restrict__ csums,
    float* __restrict__ D1, int* __restrict__ K1, float* __restrict__ D2) {
  const int b  = blockIdx.y;
  const int e  = expert_idx[b];
  const int hc = blockIdx.z;
  if (hc >= (2 << e)) return;               // inert (uniform exit)
  const int cs_off = (e == 0) ? 0 : (e == 1) ? 256 : (e == 2) ? 768 : 1792;
  const int krow0  = cs_off + hc * 128;
  const int t0     = b * 1024 + blockIdx.x * 128;

  // LDS: Ah, Al (single) + Bh0, Bl0, Bh1, Bl1 (double) @ 128 rows x 32 ushorts
  __shared__ unsigned short smem[6 * 128 * 32];   // 48 KB
  __shared__ float  sh_cs[128];
  unsigned short* Ah = smem;
  unsigned short* Al = smem + 4096;
  unsigned short* Bbase = smem + 8192;            // [sel*8192]: Bh, then Bl

  const int tid = threadIdx.x;
  if (tid < 128) sh_cs[tid] = csums[krow0 + tid];

  const int w = tid >> 6, l = tid & 63;
  const int h = w >> 2, q = w & 3;
  const int m16 = l & 15, g = l >> 4;

  // A staging geometry: thread covers rows r0 and r0+64, 4-float seg
  const int r0 = tid >> 3, sA = tid & 7;
  const size_t abase0 = (size_t)(t0 + r0) * 256 + sA * 4;
  const size_t abase1 = (size_t)(t0 + r0 + 64) * 256 + sA * 4;

  // B staging: wave w fills rows w*16..w*16+15 linearly (gll dest is
  // wave-uniform base + lane*16); global source chunk pre-swizzled.
  const int brow   = w * 16 + (l >> 2);
  const int bchunk = (l & 3) ^ ((brow >> 1) & 3);
  const size_t bsrc0 = (size_t)(krow0 + brow) * 256 + (size_t)bchunk * 8;

  f32x4 acc[4][2];
  #pragma unroll
  for (int i = 0; i < 4; ++i)
    #pragma unroll
    for (int j = 0; j < 2; ++j) acc[i][j] = (f32x4){0.f, 0.f, 0.f, 0.f};

  // ---- prologue: prefetch A(0) to regs, issue B(0) into buffer 0 ----
  float4 pa0 = *(const float4*)(z_e + abase0);
  float4 pa1 = *(const float4*)(z_e + abase1);
  gll16(cb_hi + bsrc0, Bbase + w * 512);
  gll16(cb_lo + bsrc0, Bbase + 4096 + w * 512);

  for (int kp = 0; kp < 8; ++kp) {
    const int sel = kp & 1;
    unsigned short* Bh = Bbase + sel * 8192;
    unsigned short* Bl = Bh + 4096;

    // barrier #1: previous MFMA phase's ds_reads done before A overwrite
    asm volatile("s_waitcnt lgkmcnt(0)" ::: "memory");
    __builtin_amdgcn_s_barrier();

    // convert prefetched A(kp) regs -> split bf16 -> swizzled ds_write
    {
      unsigned hxy, hzw, lxy, lzw;
      asm("v_cvt_pk_bf16_f32 %0, %1, %2" : "=v"(hxy) : "v"(pa0.x), "v"(pa0.y));
      asm("v_cvt_pk_bf16_f32 %0, %1, %2" : "=v"(hzw) : "v"(pa0.z), "v"(pa0.w));
      float lx = pa0.x - __uint_as_float(hxy << 16);
      float ly = pa0.y - __uint_as_float(hxy & 0xffff0000u);
      float lz = pa0.z - __uint_as_float(hzw << 16);
      float lw = pa0.w - __uint_as_float(hzw & 0xffff0000u);
      asm("v_cvt_pk_bf16_f32 %0, %1, %2" : "=v"(lxy) : "v"(lx), "v"(ly));
      asm("v_cvt_pk_bf16_f32 %0, %1, %2" : "=v"(lzw) : "v"(lz), "v"(lw));
      int off = r0 * 32 + ((((sA >> 1) ^ ((r0 >> 1) & 3)) << 3) | ((sA & 1) << 2));
      *(uint2*)(Ah + off) = make_uint2(hxy, hzw);
      *(uint2*)(Al + off) = make_uint2(lxy, lzw);
    }
    {
      const int r1 = r0 + 64;
      unsigned hxy, hzw, lxy, lzw;
      asm("v_cvt_pk_bf16_f32 %0, %1, %2" : "=v"(hxy) : "v"(pa1.x), "v"(pa1.y));
      asm("v_cvt_pk_bf16_f32 %0, %1, %2" : "=v"(hzw) : "v"(pa1.z), "v"(pa1.w));
      float lx = pa1.x - __uint_as_float(hxy << 16);
      float ly = pa1.y - __uint_as_float(hxy & 0xffff0000u);
      float lz = pa1.z - __uint_as_float(hzw << 16);
      float lw = pa1.w - __uint_as_float(hzw & 0xffff0000u);
      asm("v_cvt_pk_bf16_f32 %0, %1, %2" : "=v"(lxy) : "v"(lx), "v"(ly));
      asm("v_cvt_pk_bf16_f32 %0, %1, %2" : "=v"(lzw) : "v"(lz), "v"(lw));
      int off = r1 * 32 + ((((sA >> 1) ^ ((r1 >> 1) & 3)) << 3) | ((sA & 1) << 2));
      *(uint2*)(Ah + off) = make_uint2(hxy, hzw);
      *(uint2*)(Al + off) = make_uint2(lxy, lzw);
    }

    // prefetch next tile: A(kp+1) -> regs, B(kp+1) -> alternate buffer.
    // Counted wait: outstanding = [B(kp) x2 (oldest), A(kp+1) x2, B(kp+1) x2];
    // vmcnt(4) retires exactly B(kp). Last iter: nothing newer -> vmcnt(0).
    if (kp < 7) {
      const int kcn = (kp + 1) * 32;
      pa0 = *(const float4*)(z_e + abase0 + kcn);
      pa1 = *(const float4*)(z_e + abase1 + kcn);
      unsigned short* BhN = Bbase + (sel ^ 1) * 8192;
      gll16(cb_hi + bsrc0 + kcn, BhN + w * 512);
      gll16(cb_lo + bsrc0 + kcn, BhN + 4096 + w * 512);
      asm volatile("s_waitcnt vmcnt(4) lgkmcnt(0)" ::: "memory");
    } else {
      asm volatile("s_waitcnt vmcnt(0) lgkmcnt(0)" ::: "memory");
    }
    __builtin_amdgcn_s_barrier();
    __builtin_amdgcn_sched_barrier(0);

    // fragments + MFMA on A, B(sel)
    bf16x8 bh[2], bl[2];
    #pragma unroll
    for (int j = 0; j < 2; ++j) {
      int r = q * 32 + j * 16 + m16;
      int n = r * 32 + ((g ^ ((r >> 1) & 3)) << 3);
      bh[j] = *(bf16x8*)(Bh + n);
      bl[j] = *(bf16x8*)(Bl + n);
    }
    #pragma unroll
    for (int i = 0; i < 4; ++i) {
      int r = h * 64 + i * 16 + m16;
      int a = r * 32 + ((g ^ ((r >> 1) & 3)) << 3);
      bf16x8 ah = *(bf16x8*)(Ah + a);
      bf16x8 al = *(bf16x8*)(Al + a);
      #pragma unroll
      for (int j = 0; j < 2; ++j) {
        acc[i][j] = __builtin_amdgcn_mfma_f32_16x16x32_bf16(ah, bh[j], acc[i][j], 0, 0, 0);
        acc[i][j] = __builtin_amdgcn_mfma_f32_16x16x32_bf16(al, bh[j], acc[i][j], 0, 0, 0);
        acc[i][j] = __builtin_amdgcn_mfma_f32_16x16x32_bf16(ah, bl[j], acc[i][j], 0, 0, 0);
      }
    }
  }

  __syncthreads();
  float* mD = (float*)smem;
  int*   mK = (int*)(smem + 1024);
  float* mS = (float*)(smem + 2048);

  #pragma unroll
  for (int i = 0; i < 4; ++i) {
    #pragma unroll
    for (int r = 0; r < 4; ++r) {
      int k0 = q * 32 + m16;
      float d0 = sh_cs[k0]      - 2.0f * acc[i][0][r];
      float d1 = sh_cs[k0 + 16] - 2.0f * acc[i][1][r];
      float bv, sv; int bk;
      if (d0 <= d1) { bv = d0; bk = k0; sv = d1; }
      else          { bv = d1; bk = k0 + 16; sv = d0; }
      #pragma unroll
      for (int off = 8; off >= 1; off >>= 1) {
        float ov = __shfl_xor(bv, off);
        int   ok = __shfl_xor(bk, off);
        float os = __shfl_xor(sv, off);
        float nb; int nk;
        if (ov < bv || (ov == bv && ok < bk)) { nb = ov; nk = ok; }
        else                                  { nb = bv; nk = bk; }
        sv = fminf(fmaxf(bv, ov), fminf(sv, os));
        bv = nb; bk = nk;
      }
      if (m16 == 0) {
        int tloc = h * 64 + i * 16 + g * 4 + r;
        mD[tloc * 4 + q] = bv;
        mK[tloc * 4 + q] = bk;
        mS[tloc * 4 + q] = sv;
      }
    }
  }
  __syncthreads();
  if (tid < 128) {
    float B = 3.4e38f, S = 3.4e38f; int Kb = 0;
    #pragma unroll
    for (int c = 0; c < 4; ++c) {
      float d1v = mD[tid * 4 + c];
      int   k1v = mK[tid * 4 + c];
      float d2v = mS[tid * 4 + c];
      S = fminf(fmaxf(B, d1v), fminf(S, d2v));
      if (d1v < B) { B = d1v; Kb = k1v; }
    }
    int tg = t0 + tid;
    D1[hc * NTOK + tg] = B;
    K1[hc * NTOK + tg] = hc * 128 + Kb;
    D2[hc * NTOK + tg] = S;
  }
}

// ---------------- combine: merge half-chunks -> idx, worklist, loss partials ----------------
__global__ __launch_bounds__(256) void combine_kernel(
    const int* __restrict__ expert_idx,
    const float* __restrict__ D1, const int* __restrict__ K1,
    const float* __restrict__ D2,
    float* __restrict__ idx_out,
    int* __restrict__ wl, int* __restrict__ wl_cnt,
    double* __restrict__ parts) {
  const int t = blockIdx.x * 256 + threadIdx.x;
  const int e = expert_idx[t >> 10];
  const int nch = 2 << e;
  float B = 3.4e38f, S = 3.4e38f; int Kb = 0;
  for (int c = 0; c < nch; ++c) {
    float d1 = D1[c * NTOK + t];
    int   k1 = K1[c * NTOK + t];
    float d2 = D2[c * NTOK + t];
    S = fminf(fmaxf(B, d1), fminf(S, d2));
    if (d1 < B) { B = d1; Kb = k1; }
  }
  idx_out[t] = (float)Kb;
  if (S - B < EPS_GAP) {                     // fused compact
    int p = atomicAdd(wl_cnt, 1);
    wl[p] = t;
  }
  double s = (double)B;
  #pragma unroll
  for (int off = 32; off >= 1; off >>= 1) s += __shfl_down(s, off, 64);
  __shared__ double sh[4];
  if ((threadIdx.x & 63) == 0) sh[threadIdx.x >> 6] = s;
  __syncthreads();
  if (threadIdx.x == 0) parts[blockIdx.x] = sh[0] + sh[1] + sh[2] + sh[3];
}

// ---------------- zq gather: one wave per token ----------------
__global__ __launch_bounds__(256) void zq_gather_kernel(
    const int* __restrict__ expert_idx,
    const float* __restrict__ cb0, const float* __restrict__ cb1,
    const float* __restrict__ cb2, const float* __restrict__ cb3,
    const float* __restrict__ idx_out, float* __restrict__ zq_out) {
  const int tok  = blockIdx.x * 4 + (threadIdx.x >> 6);
  const int lane = threadIdx.x & 63;
  const int e = expert_idx[tok >> 10];
  const float* cb = (e == 0) ? cb0 : (e == 1) ? cb1 : (e == 2) ? cb2 : cb3;
  const int row = (int)idx_out[tok];
  ((float4*)(zq_out + (size_t)tok * 256))[lane] =
      ((const float4*)(cb + (size_t)row * 256))[lane];
}

// ---------------- rescue: numpy-fp32-EMULATED re-rank, one block per flagged token ----------------
__global__ __launch_bounds__(256) void rescue_kernel(
    const float* __restrict__ z_e, const int* __restrict__ expert_idx,
    const float* __restrict__ cb0, const float* __restrict__ cb1,
    const float* __restrict__ cb2, const float* __restrict__ cb3,
    const double* __restrict__ csums64,
    const int* __restrict__ wl, const int* __restrict__ wl_cnt,
    float* __restrict__ zq_out, float* __restrict__ idx_out) {
  __shared__ float  szrow[256];
  __shared__ double szs[4];
  __shared__ float  sdv[3][256];
  __shared__ int    skv[3][256];
  __shared__ int    s_kc;
  const int tid = threadIdx.x;
  const int wid = tid >> 6, lane = tid & 63;
  const int n = wl_cnt[0];
  for (int it = blockIdx.x; it < n; it += gridDim.x) {
    const int t = wl[it];
    const int b = t >> 10;
    const int e = expert_idx[b];
    const int K = 256 << e;
    const float* cb = (e == 0) ? cb0 : (e == 1) ? cb1 : (e == 2) ? cb2 : cb3;
    const int off = (e == 0) ? 0 : (e == 1) ? 256 : (e == 2) ? 768 : 1792;
    const double* cs64 = csums64 + off;

    __syncthreads();                       // protect shared reuse across iterations
    float zv = z_e[(size_t)t * 256 + tid];
    szrow[tid] = zv;
    double zsq = (double)zv * (double)zv;
    #pragma unroll
    for (int o = 32; o >= 1; o >>= 1) zsq += __shfl_down(zsq, o, 64);
    if (lane == 0) szs[wid] = zsq;
    __syncthreads();
    const float zs_mid = (float)(szs[0] + szs[1] + szs[2] + szs[3]);
    const unsigned zu = __float_as_uint(zs_mid);
    float zs[3] = {__uint_as_float(zu - 1), zs_mid, __uint_as_float(zu + 1)};

    float bd[3] = {3.4e38f, 3.4e38f, 3.4e38f};
    int   bk[3] = {1 << 30, 1 << 30, 1 << 30};
    const float4* z4 = (const float4*)szrow;
    for (int k = tid; k < K; k += 256) {
      const float4* c4 = (const float4*)(cb + (size_t)k * 256);
      double d0 = 0.0, d1v = 0.0, d2v = 0.0, d3 = 0.0;   // 4 indep chains
      for (int qq = 0; qq < 64; qq += 4) {
        float4 a0 = z4[qq],     c0 = c4[qq];
        float4 a1 = z4[qq + 1], c1 = c4[qq + 1];
        float4 a2 = z4[qq + 2], c2 = c4[qq + 2];
        float4 a3 = z4[qq + 3], c3 = c4[qq + 3];
        d0 += (double)a0.x*c0.x + (double)a0.y*c0.y + (double)a0.z*c0.z + (double)a0.w*c0.w;
        d1v+= (double)a1.x*c1.x + (double)a1.y*c1.y + (double)a1.z*c1.z + (double)a1.w*c1.w;
        d2v+= (double)a2.x*c2.x + (double)a2.y*c2.y + (double)a2.z*c2.z + (double)a2.w*c2.w;
        d3 += (double)a3.x*c3.x + (double)a3.y*c3.y + (double)a3.z*c3.z + (double)a3.w*c3.w;
      }
      double dot = (d0 + d1v) + (d2v + d3);
      const float c32 = (float)cs64[k];
      const float m2d = (float)(2.0 * dot);
      #pragma unroll
      for (int v = 0; v < 3; ++v) {
        float T1  = zs[v] + c32;           // numpy order: (zsum+csum) - 2dot
        float d32 = T1 - m2d;
        if (d32 < bd[v]) { bd[v] = d32; bk[v] = k; }
      }
    }
    #pragma unroll
    for (int v = 0; v < 3; ++v) { sdv[v][tid] = bd[v]; skv[v][tid] = bk[v]; }
    __syncthreads();
    for (int s = 128; s >= 1; s >>= 1) {
      if (tid < s) {
        #pragma unroll
        for (int v = 0; v < 3; ++v) {
          float od = sdv[v][tid + s]; int ok = skv[v][tid + s];
          if (od < sdv[v][tid] || (od == sdv[v][tid] && ok < skv[v][tid])) {
            sdv[v][tid] = od; skv[v][tid] = ok;
          }
        }
      }
      __syncthreads();
    }
    if (tid == 0) {
      int k0 = skv[0][0], k1 = skv[1][0], k2 = skv[2][0];
      int kc = (k0 == k2) ? k0 : k1;       // majority vote over zsum ulp variants
      s_kc = kc;
      idx_out[t] = (float)kc;
    }
    __syncthreads();
    const int kc = s_kc;
    if (tid < 64)
      ((float4*)(zq_out + (size_t)t * 256))[tid] =
          ((const float4*)(cb + (size_t)kc * 256))[tid];
  }
}

// ---------------- finalize: loss = 1.25*(S_comb + S_zsq)/2^32 ----------------
__global__ __launch_bounds__(256) void finalize_kernel(
    const double* __restrict__ parts_comb, const double* __restrict__ parts_zsq,
    float* __restrict__ loss_out) {
  const int tid = threadIdx.x;
  double s = parts_comb[tid] + parts_zsq[tid] + parts_zsq[tid + 256]
           + parts_zsq[tid + 512] + parts_zsq[tid + 768];
  #pragma unroll
  for (int off = 32; off >= 1; off >>= 1) s += __shfl_down(s, off, 64);
  __shared__ double sh[4];
  if ((tid & 63) == 0) sh[tid >> 6] = s;
  __syncthreads();
  if (tid == 0)
    loss_out[0] = (float)((sh[0] + sh[1] + sh[2] + sh[3]) * (1.25 / 4294967296.0));
}

extern "C" void kernel_launch(void* const* d_in, const int* in_sizes, int n_in,
                              void* d_out, int out_size, void* d_ws, size_t ws_size,
                              hipStream_t stream) {
  const float* z_e  = (const float*)d_in[0];
  const int*   eidx = (const int*)d_in[1];
  const float* cb0  = (const float*)d_in[2];
  const float* cb1  = (const float*)d_in[3];
  const float* cb2  = (const float*)d_in[4];
  const float* cb3  = (const float*)d_in[5];

  float* zq    = (float*)d_out;                       // 64*1024*256
  float* idxf  = (float*)d_out + 16777216;            // 64*1024 as floats
  float* lossf = (float*)d_out + 16777216 + 65536;    // 1

  char* wsp = (char*)d_ws;
  double*         parts_comb = (double*)wsp;           wsp += 256 * 8;
  double*         parts_zsq  = (double*)wsp;           wsp += 1024 * 8;
  double*         csums64    = (double*)wsp;           wsp += 3840 * 8;
  float*          csums      = (float*)wsp;            wsp += 3840 * 4;
  int*            wl_cnt     = (int*)wsp;              wsp += 16;
  int*            wl         = (int*)wsp;              wsp += NTOK * 4;
  unsigned short* cb_hi      = (unsigned short*)wsp;   wsp += 3840 * 256 * 2;
  unsigned short* cb_lo      = (unsigned short*)wsp;   wsp += 3840 * 256 * 2;
  float*          D1         = (float*)wsp;            wsp += 16 * NTOK * 4;
  int*            K1         = (int*)wsp;              wsp += 16 * NTOK * 4;
  float*          D2         = (float*)wsp;            wsp += 16 * NTOK * 4;

  csum_split_kernel<<<960, 256, 0, stream>>>(cb0, cb1, cb2, cb3,
                                             csums, csums64, cb_hi, cb_lo, wl_cnt);
  zsq_kernel<<<1024, 256, 0, stream>>>(z_e, parts_zsq);
  dim3 grid(8, 64, 16);
  vq_mfma<<<grid, 512, 0, stream>>>(z_e, eidx, cb_hi, cb_lo, csums, D1, K1, D2);
  combine_kernel<<<256, 256, 0, stream>>>(eidx, D1, K1, D2, idxf, wl, wl_cnt, parts_comb);
  zq_gather_kernel<<<16384, 256, 0, stream>>>(eidx, cb0, cb1, cb2, cb3, idxf, zq);
  rescue_kernel<<<2048, 256, 0, stream>>>(z_e, eidx, cb0, cb1, cb2, cb3,
                                          csums64, wl, wl_cnt, zq, idxf);
  finalize_kernel<<<1, 256, 0, stream>>>(parts_comb, parts_zsq, lossf);
}